// Round 14
// baseline (7308.290 us; speedup 1.0000x reference)
//
#include <hip/hip_runtime.h>

// Residual VQ — bf16-MFMA screen + np-exact windowed rescore (round 14).
//
// Screen: s~[t][k] = C_k - 2*(r~ . c~) via mfma_f32_16x16x32_bf16, r~/c~ =
// RNE bf16 of the exact values. Worst-case |s~ - (dist-A)| <= ~0.03
// (||r||~16, ||c||~0.32, rel 2^-8); window W=0.6 (20x margin) => candidate
// list provably contains the np-argmin and all f32-grid ties.
// Rescore: np-exact chain (validated r4-r13): dot = sequential fmaf d=0..255,
// dist = fl(fl(A - fl(2 dot)) + C), lex (dist,k) min == first-index ties.
// Safety: alarm (|exact-A - s~min| > 0.3) or list overflow => full exact
// scan for that token (layout bug => slow-but-correct, not wrong).
//
// Fragment packing: A (r~, LDS rb) lane l: m = l&15, k = (l>>4)*8 + j.
// B (c~, ws cbf, pre-permuted) lane l: n = l&15, same k map. A/B use the
// SAME (group,j)->k bijection, so the MFMA dot is correct under either
// documented intra-lane k-order. C/D layout (HW-verified): col = lane&15,
// row = (lane>>4)*4 + reg.
//
// Org: block = 32 tokens, 512 thr / 8 waves; wave w owns k in [128w,128w+128)
// (8 n-tiles of 16). acc f32x4[2 mt][8 nt]. 5 barriers/level.

#define NTOK 131072
#define DEPTH 8
#define KCB 1024
#define DIM 256
#define TM 32
#define RP 260
#define RBP 264
#define WWIN 0.6f
#define ALARM 0.3f
#define LCAP 64

typedef __attribute__((ext_vector_type(8))) short short8v;
typedef __attribute__((ext_vector_type(4))) float f32x4;

__device__ __forceinline__ unsigned short f32_to_bf16_rne(float f) {
  unsigned int u = __float_as_uint(f);
  return (unsigned short)((u + 0x7FFFu + ((u >> 16) & 1u)) >> 16);
}

__device__ __forceinline__ float np_sumsq_128(const float* p) {
  float s[16];
#pragma unroll
  for (int l = 0; l < 16; ++l) {
    float r0 = __fadd_rn(__fmul_rn(p[l], p[l]),
                         __fmul_rn(p[l + 64], p[l + 64]));
    float r1 = __fadd_rn(__fmul_rn(p[l + 16], p[l + 16]),
                         __fmul_rn(p[l + 80], p[l + 80]));
    float r2 = __fadd_rn(__fmul_rn(p[l + 32], p[l + 32]),
                         __fmul_rn(p[l + 96], p[l + 96]));
    float r3 = __fadd_rn(__fmul_rn(p[l + 48], p[l + 48]),
                         __fmul_rn(p[l + 112], p[l + 112]));
    s[l] = __fadd_rn(__fadd_rn(r0, r1), __fadd_rn(r2, r3));
  }
  float t[8];
#pragma unroll
  for (int l = 0; l < 8; ++l) t[l] = __fadd_rn(s[l], s[l + 8]);
  float u[4];
#pragma unroll
  for (int l = 0; l < 4; ++l) u[l] = __fadd_rn(t[l], t[l + 4]);
  return __fadd_rn(__fadd_rn(u[0], u[2]), __fadd_rn(u[1], u[3]));
}

__device__ __forceinline__ float np_sumsq_256(const float* p) {
  return __fadd_rn(np_sumsq_128(p), np_sumsq_128(p + 128));
}

// np-exact distance for one (token,k): sequential d-ascending fmaf chain.
__device__ __forceinline__ float np_dist(const float* rrow, const float* crow,
                                         float A, float C) {
  float dot = 0.f;
#pragma unroll 8
  for (int q = 0; q < 64; ++q) {
    float4 rv = *(const float4*)(rrow + q * 4);
    float4 cv = *(const float4*)(crow + q * 4);
    dot = fmaf(rv.x, cv.x, dot);
    dot = fmaf(rv.y, cv.y, dot);
    dot = fmaf(rv.z, cv.z, dot);
    dot = fmaf(rv.w, cv.w, dot);
  }
  return __fadd_rn(__fsub_rn(A, __fmul_rn(2.0f, dot)), C);
}

__global__ __launch_bounds__(256) void c2_kernel(const float* __restrict__ cbs,
                                                 float* __restrict__ C32g) {
  int gid = blockIdx.x * 256 + threadIdx.x;
  C32g[gid] = np_sumsq_256(cbs + (size_t)gid * DIM);
}

// cbf[(((lvl*64+nt)*8+s)*64+lane)*8 + j] = bf16(cbs[lvl][nt*16+(lane&15)]
//                                               [s*32+(lane>>4)*8+j])
__global__ __launch_bounds__(256) void pack_kernel(
    const float* __restrict__ cbs, unsigned short* __restrict__ cbf) {
  int gid = blockIdx.x * 256 + threadIdx.x;  // 8*64*8*64 = 262144
  int lane = gid & 63;
  int s = (gid >> 6) & 7;
  int nt = (gid >> 9) & 63;
  int lvl = gid >> 15;
  int kcol = nt * 16 + (lane & 15);
  int kd0 = s * 32 + (lane >> 4) * 8;
  const float* src = cbs + ((size_t)lvl * KCB + kcol) * DIM + kd0;
  unsigned short t[8];
#pragma unroll
  for (int j = 0; j < 8; ++j) t[j] = f32_to_bf16_rne(src[j]);
  ushort4 lo = {t[0], t[1], t[2], t[3]};
  ushort4 hi = {t[4], t[5], t[6], t[7]};
  *(ushort4*)(cbf + (size_t)gid * 8) = lo;
  *(ushort4*)(cbf + (size_t)gid * 8 + 4) = hi;
}

__global__ __launch_bounds__(512, 1) void rvq_kernel(
    const float* __restrict__ latent, const float* __restrict__ cbs,
    const float* __restrict__ C32g, const unsigned short* __restrict__ cbf,
    float* __restrict__ out) {
  __shared__ float r_m[TM][RP];                       // exact f32 residual
  __shared__ __align__(16) unsigned short rb[TM * RBP];  // bf16 residual
  __shared__ float A_s[TM];
  __shared__ float smin_s[8][TM];
  __shared__ float gmin_s[TM];
  __shared__ int cnt[TM];
  __shared__ int list[TM][LCAP];
  __shared__ int idx_s[TM];

  const int tid = threadIdx.x;
  const int w = tid >> 6;
  const int lane = tid & 63;
  const int lc = lane & 15;   // col / m within tile
  const int lg = lane >> 4;   // k-group
  const int n0 = blockIdx.x * TM;

  // ---- stage latent -> r_m (exact) + rb (bf16) ----
  {
    int tok = tid >> 4;
    int db = (tid & 15) * 16;
    const float* src = latent + (size_t)(n0 + tok) * DIM + db;
#pragma unroll
    for (int j = 0; j < 4; ++j) {
      float4 v = *(const float4*)(src + j * 4);
      *(float4*)&r_m[tok][db + j * 4] = v;
      rb[tok * RBP + db + j * 4 + 0] = f32_to_bf16_rne(v.x);
      rb[tok * RBP + db + j * 4 + 1] = f32_to_bf16_rne(v.y);
      rb[tok * RBP + db + j * 4 + 2] = f32_to_bf16_rne(v.z);
      rb[tok * RBP + db + j * 4 + 3] = f32_to_bf16_rne(v.w);
    }
  }
  __syncthreads();

  for (int lvl = 0; lvl < DEPTH; ++lvl) {
    const float* cb = cbs + (size_t)lvl * KCB * DIM;

    // P1: exact A (np pairwise) — ordered before rescore by B1..B3
    if (tid < TM) A_s[tid] = np_sumsq_256(&r_m[tid][0]);

    // P2: MFMA screen over this wave's 128 k
    f32x4 acc[2][8];
#pragma unroll
    for (int mt = 0; mt < 2; ++mt)
#pragma unroll
      for (int nt = 0; nt < 8; ++nt) acc[mt][nt] = (f32x4){0.f, 0.f, 0.f, 0.f};

    {
      const unsigned short* bbase =
          cbf + ((((size_t)lvl * 64 + w * 8) * 8 + 0) * 64 + lane) * 8;
#pragma unroll
      for (int s = 0; s < 8; ++s) {
        short8v a0 = *(const short8v*)&rb[(0 * 16 + lc) * RBP + s * 32 + lg * 8];
        short8v a1 = *(const short8v*)&rb[(1 * 16 + lc) * RBP + s * 32 + lg * 8];
        const unsigned short* bp = bbase + (size_t)s * 64 * 8;
#pragma unroll
        for (int nt = 0; nt < 8; ++nt) {
          short8v bv = *(const short8v*)(bp + (size_t)nt * 8 * 64 * 8);
          acc[0][nt] = __builtin_amdgcn_mfma_f32_16x16x32_bf16(
              a0, bv, acc[0][nt], 0, 0, 0);
          acc[1][nt] = __builtin_amdgcn_mfma_f32_16x16x32_bf16(
              a1, bv, acc[1][nt], 0, 0, 0);
        }
      }
    }

    // transform acc -> s~ = C_k - 2*dot; track per-lane per-token min
    float Cv[8];
#pragma unroll
    for (int nt = 0; nt < 8; ++nt)
      Cv[nt] = C32g[lvl * KCB + w * 128 + nt * 16 + lc];
    float tmin[2][4];
#pragma unroll
    for (int mt = 0; mt < 2; ++mt)
#pragma unroll
      for (int reg = 0; reg < 4; ++reg) tmin[mt][reg] = 3.4e38f;
#pragma unroll
    for (int mt = 0; mt < 2; ++mt)
#pragma unroll
      for (int nt = 0; nt < 8; ++nt) {
        f32x4 sc;
#pragma unroll
        for (int reg = 0; reg < 4; ++reg) {
          float v = __fsub_rn(Cv[nt], __fmul_rn(2.0f, acc[mt][nt][reg]));
          sc[reg] = v;
          tmin[mt][reg] = fminf(tmin[mt][reg], v);
        }
        acc[mt][nt] = sc;  // keep s~ for append phase
      }
    // wave-local value-min across the 16 cols (xor within 16-lane group)
#pragma unroll
    for (int m = 1; m <= 8; m <<= 1)
#pragma unroll
      for (int mt = 0; mt < 2; ++mt)
#pragma unroll
        for (int reg = 0; reg < 4; ++reg)
          tmin[mt][reg] = fminf(tmin[mt][reg], __shfl_xor(tmin[mt][reg], m));
    if (lc == 0) {
#pragma unroll
      for (int mt = 0; mt < 2; ++mt)
#pragma unroll
        for (int reg = 0; reg < 4; ++reg)
          smin_s[w][mt * 16 + lg * 4 + reg] = tmin[mt][reg];
    }
    __syncthreads();  // B1

    // P3: global screen-min + reset counters
    if (tid < TM) {
      float g = smin_s[0][tid];
#pragma unroll
      for (int ww = 1; ww < 8; ++ww) g = fminf(g, smin_s[ww][tid]);
      gmin_s[tid] = g;
      cnt[tid] = 0;
    }
    __syncthreads();  // B2

    // P4: append window members
#pragma unroll
    for (int mt = 0; mt < 2; ++mt)
#pragma unroll
      for (int reg = 0; reg < 4; ++reg) {
        int t = mt * 16 + lg * 4 + reg;
        float th = gmin_s[t] + WWIN;
#pragma unroll
        for (int nt = 0; nt < 8; ++nt) {
          if (acc[mt][nt][reg] <= th) {
            int slot = atomicAdd(&cnt[t], 1);
            if (slot < LCAP) list[t][slot] = w * 128 + nt * 16 + lc;
          }
        }
      }
    __syncthreads();  // B3

    // P5: np-exact rescore of candidates (16 threads per token)
    {
      int t = tid >> 4;
      int kc = tid & 15;
      float A = A_s[t];
      int n = cnt[t];
      float bd = 3.4e38f;
      int bk = KCB;
      if (n <= LCAP) {
        for (int ci = kc; ci < n; ci += 16) {
          int k = list[t][ci];
          float d = np_dist(&r_m[t][0], cb + (size_t)k * DIM, A,
                            C32g[lvl * KCB + k]);
          if (d < bd || (d == bd && k < bk)) {
            bd = d;
            bk = k;
          }
        }
      }
#pragma unroll
      for (int m = 1; m <= 8; m <<= 1) {
        float od = __shfl_xor(bd, m);
        int ok = __shfl_xor(bk, m);
        if (od < bd || (od == bd && ok < bk)) {
          bd = od;
          bk = ok;
        }
      }
      // safety: overflow or screen/exact disagreement -> full exact scan
      bool redo = (n > LCAP) ||
                  (fabsf(__fsub_rn(bd, A) - gmin_s[t]) > (WWIN - ALARM));
      if (redo) {
        bd = 3.4e38f;
        bk = KCB;
        for (int k = kc; k < KCB; k += 16) {
          float d = np_dist(&r_m[t][0], cb + (size_t)k * DIM, A,
                            C32g[lvl * KCB + k]);
          if (d < bd || (d == bd && k < bk)) {
            bd = d;
            bk = k;
          }
        }
#pragma unroll
        for (int m = 1; m <= 8; m <<= 1) {
          float od = __shfl_xor(bd, m);
          int ok = __shfl_xor(bk, m);
          if (od < bd || (od == bd && ok < bk)) {
            bd = od;
            bk = ok;
          }
        }
      }
      if (kc == 0) {
        idx_s[t] = bk;
        out[(size_t)NTOK * DIM + (size_t)lvl * NTOK + n0 + t] = (float)bk;
      }
    }
    __syncthreads();  // B4

    // P6: residual update (exact) + rb refresh (same thread, same slice)
    {
      int tok = tid >> 4;
      int db = (tid & 15) * 16;
      const float* crow = cb + (size_t)idx_s[tok] * DIM + db;
#pragma unroll
      for (int j = 0; j < 4; ++j) {
        float4 cv4 = *(const float4*)(crow + j * 4);
        int d = db + j * 4;
        float x0 = __fsub_rn(r_m[tok][d + 0], cv4.x);
        float x1 = __fsub_rn(r_m[tok][d + 1], cv4.y);
        float x2 = __fsub_rn(r_m[tok][d + 2], cv4.z);
        float x3 = __fsub_rn(r_m[tok][d + 3], cv4.w);
        r_m[tok][d + 0] = x0;
        r_m[tok][d + 1] = x1;
        r_m[tok][d + 2] = x2;
        r_m[tok][d + 3] = x3;
        rb[tok * RBP + d + 0] = f32_to_bf16_rne(x0);
        rb[tok * RBP + d + 1] = f32_to_bf16_rne(x1);
        rb[tok * RBP + d + 2] = f32_to_bf16_rne(x2);
        rb[tok * RBP + d + 3] = f32_to_bf16_rne(x3);
      }
    }
    __syncthreads();  // B5
  }

  // ---- straight_through = fl(l + fl(q - l)), q = fl(l - r) ----
  {
    int tok = tid >> 4;
    int db = (tid & 15) * 16;
#pragma unroll
    for (int j = 0; j < 4; ++j) {
      int d = db + j * 4;
      size_t gi = (size_t)(n0 + tok) * DIM + d;
      float4 l4 = *(const float4*)(latent + gi);
      float4 qv;
      float q;
      q = __fsub_rn(l4.x, r_m[tok][d + 0]);
      qv.x = __fadd_rn(l4.x, __fsub_rn(q, l4.x));
      q = __fsub_rn(l4.y, r_m[tok][d + 1]);
      qv.y = __fadd_rn(l4.y, __fsub_rn(q, l4.y));
      q = __fsub_rn(l4.z, r_m[tok][d + 2]);
      qv.z = __fadd_rn(l4.z, __fsub_rn(q, l4.z));
      q = __fsub_rn(l4.w, r_m[tok][d + 3]);
      qv.w = __fadd_rn(l4.w, __fsub_rn(q, l4.w));
      *(float4*)(out + gi) = qv;
    }
  }
}

extern "C" void kernel_launch(void* const* d_in, const int* in_sizes, int n_in,
                              void* d_out, int out_size, void* d_ws,
                              size_t ws_size, hipStream_t stream) {
  const float* latent = (const float*)d_in[0];
  const float* codebooks = (const float*)d_in[1];
  float* out = (float*)d_out;
  float* C32g = (float*)d_ws;                       // 32 KB
  unsigned short* cbf = (unsigned short*)((char*)d_ws + 32768);  // 4 MB
  // ws requirement 4.23 MB; r13 demonstrated >= 8.4 MB available.

  hipLaunchKernelGGL(c2_kernel, dim3(DEPTH * KCB / 256), dim3(256), 0, stream,
                     codebooks, C32g);
  hipLaunchKernelGGL(pack_kernel, dim3(DEPTH * 64 * 8 * 64 / 256), dim3(256),
                     0, stream, codebooks, cbf);
  hipLaunchKernelGGL(rvq_kernel, dim3(NTOK / TM), dim3(512), 0, stream, latent,
                     codebooks, C32g, cbf, out);
}

// Round 15
// 3248.819 us; speedup vs baseline: 2.2495x; 2.2495x over previous
//
#include <hip/hip_runtime.h>

// Residual VQ — bf16-MFMA screen + np-exact windowed rescore (round 15).
// r14 PASS but rescore-traffic-bound: W=0.6 admitted ~18 cand/token-level
// (19 GB scattered reads, 4.5 GB HBM fetch, VALUBusy 8%). W=0.2 (~100 sigma
// of measured screen-error distribution; hard ties at 3e-5 unaffected) cuts
// candidates ~6x. Everything else identical to the validated r14 kernel.
//
// Screen: s~ = C_k - 2*(r~.c~) via mfma_f32_16x16x32_bf16 (RNE bf16 inputs).
// Rescore: np-exact chain (validated r4-r14): dot = sequential fmaf d=0..255,
// dist = fl(fl(A - fl(2 dot)) + C), lex (dist,k) min == first-index ties.
// Safety: list overflow or screen/exact disagreement > 0.15 => full exact
// scan for that token.

#define NTOK 131072
#define DEPTH 8
#define KCB 1024
#define DIM 256
#define TM 32
#define RP 260
#define RBP 264
#define WWIN 0.2f
#define ALARM 0.05f
#define LCAP 64

typedef __attribute__((ext_vector_type(8))) short short8v;
typedef __attribute__((ext_vector_type(4))) float f32x4;

__device__ __forceinline__ unsigned short f32_to_bf16_rne(float f) {
  unsigned int u = __float_as_uint(f);
  return (unsigned short)((u + 0x7FFFu + ((u >> 16) & 1u)) >> 16);
}

__device__ __forceinline__ float np_sumsq_128(const float* p) {
  float s[16];
#pragma unroll
  for (int l = 0; l < 16; ++l) {
    float r0 = __fadd_rn(__fmul_rn(p[l], p[l]),
                         __fmul_rn(p[l + 64], p[l + 64]));
    float r1 = __fadd_rn(__fmul_rn(p[l + 16], p[l + 16]),
                         __fmul_rn(p[l + 80], p[l + 80]));
    float r2 = __fadd_rn(__fmul_rn(p[l + 32], p[l + 32]),
                         __fmul_rn(p[l + 96], p[l + 96]));
    float r3 = __fadd_rn(__fmul_rn(p[l + 48], p[l + 48]),
                         __fmul_rn(p[l + 112], p[l + 112]));
    s[l] = __fadd_rn(__fadd_rn(r0, r1), __fadd_rn(r2, r3));
  }
  float t[8];
#pragma unroll
  for (int l = 0; l < 8; ++l) t[l] = __fadd_rn(s[l], s[l + 8]);
  float u[4];
#pragma unroll
  for (int l = 0; l < 4; ++l) u[l] = __fadd_rn(t[l], t[l + 4]);
  return __fadd_rn(__fadd_rn(u[0], u[2]), __fadd_rn(u[1], u[3]));
}

__device__ __forceinline__ float np_sumsq_256(const float* p) {
  return __fadd_rn(np_sumsq_128(p), np_sumsq_128(p + 128));
}

// np-exact distance for one (token,k): sequential d-ascending fmaf chain.
__device__ __forceinline__ float np_dist(const float* rrow, const float* crow,
                                         float A, float C) {
  float dot = 0.f;
#pragma unroll 8
  for (int q = 0; q < 64; ++q) {
    float4 rv = *(const float4*)(rrow + q * 4);
    float4 cv = *(const float4*)(crow + q * 4);
    dot = fmaf(rv.x, cv.x, dot);
    dot = fmaf(rv.y, cv.y, dot);
    dot = fmaf(rv.z, cv.z, dot);
    dot = fmaf(rv.w, cv.w, dot);
  }
  return __fadd_rn(__fsub_rn(A, __fmul_rn(2.0f, dot)), C);
}

__global__ __launch_bounds__(256) void c2_kernel(const float* __restrict__ cbs,
                                                 float* __restrict__ C32g) {
  int gid = blockIdx.x * 256 + threadIdx.x;
  C32g[gid] = np_sumsq_256(cbs + (size_t)gid * DIM);
}

// cbf[(((lvl*64+nt)*8+s)*64+lane)*8 + j] = bf16(cbs[lvl][nt*16+(lane&15)]
//                                               [s*32+(lane>>4)*8+j])
__global__ __launch_bounds__(256) void pack_kernel(
    const float* __restrict__ cbs, unsigned short* __restrict__ cbf) {
  int gid = blockIdx.x * 256 + threadIdx.x;  // 8*64*8*64 = 262144
  int lane = gid & 63;
  int s = (gid >> 6) & 7;
  int nt = (gid >> 9) & 63;
  int lvl = gid >> 15;
  int kcol = nt * 16 + (lane & 15);
  int kd0 = s * 32 + (lane >> 4) * 8;
  const float* src = cbs + ((size_t)lvl * KCB + kcol) * DIM + kd0;
  unsigned short t[8];
#pragma unroll
  for (int j = 0; j < 8; ++j) t[j] = f32_to_bf16_rne(src[j]);
  ushort4 lo = {t[0], t[1], t[2], t[3]};
  ushort4 hi = {t[4], t[5], t[6], t[7]};
  *(ushort4*)(cbf + (size_t)gid * 8) = lo;
  *(ushort4*)(cbf + (size_t)gid * 8 + 4) = hi;
}

__global__ __launch_bounds__(512, 1) void rvq_kernel(
    const float* __restrict__ latent, const float* __restrict__ cbs,
    const float* __restrict__ C32g, const unsigned short* __restrict__ cbf,
    float* __restrict__ out) {
  __shared__ float r_m[TM][RP];                       // exact f32 residual
  __shared__ __align__(16) unsigned short rb[TM * RBP];  // bf16 residual
  __shared__ float A_s[TM];
  __shared__ float smin_s[8][TM];
  __shared__ float gmin_s[TM];
  __shared__ int cnt[TM];
  __shared__ int list[TM][LCAP];
  __shared__ int idx_s[TM];

  const int tid = threadIdx.x;
  const int w = tid >> 6;
  const int lane = tid & 63;
  const int lc = lane & 15;   // col / m within tile
  const int lg = lane >> 4;   // k-group
  const int n0 = blockIdx.x * TM;

  // ---- stage latent -> r_m (exact) + rb (bf16) ----
  {
    int tok = tid >> 4;
    int db = (tid & 15) * 16;
    const float* src = latent + (size_t)(n0 + tok) * DIM + db;
#pragma unroll
    for (int j = 0; j < 4; ++j) {
      float4 v = *(const float4*)(src + j * 4);
      *(float4*)&r_m[tok][db + j * 4] = v;
      rb[tok * RBP + db + j * 4 + 0] = f32_to_bf16_rne(v.x);
      rb[tok * RBP + db + j * 4 + 1] = f32_to_bf16_rne(v.y);
      rb[tok * RBP + db + j * 4 + 2] = f32_to_bf16_rne(v.z);
      rb[tok * RBP + db + j * 4 + 3] = f32_to_bf16_rne(v.w);
    }
  }
  __syncthreads();

  for (int lvl = 0; lvl < DEPTH; ++lvl) {
    const float* cb = cbs + (size_t)lvl * KCB * DIM;

    // P1: exact A (np pairwise) — ordered before rescore by B1..B3
    if (tid < TM) A_s[tid] = np_sumsq_256(&r_m[tid][0]);

    // P2: MFMA screen over this wave's 128 k
    f32x4 acc[2][8];
#pragma unroll
    for (int mt = 0; mt < 2; ++mt)
#pragma unroll
      for (int nt = 0; nt < 8; ++nt) acc[mt][nt] = (f32x4){0.f, 0.f, 0.f, 0.f};

    {
      const unsigned short* bbase =
          cbf + ((((size_t)lvl * 64 + w * 8) * 8 + 0) * 64 + lane) * 8;
#pragma unroll
      for (int s = 0; s < 8; ++s) {
        short8v a0 = *(const short8v*)&rb[(0 * 16 + lc) * RBP + s * 32 + lg * 8];
        short8v a1 = *(const short8v*)&rb[(1 * 16 + lc) * RBP + s * 32 + lg * 8];
        const unsigned short* bp = bbase + (size_t)s * 64 * 8;
#pragma unroll
        for (int nt = 0; nt < 8; ++nt) {
          short8v bv = *(const short8v*)(bp + (size_t)nt * 8 * 64 * 8);
          acc[0][nt] = __builtin_amdgcn_mfma_f32_16x16x32_bf16(
              a0, bv, acc[0][nt], 0, 0, 0);
          acc[1][nt] = __builtin_amdgcn_mfma_f32_16x16x32_bf16(
              a1, bv, acc[1][nt], 0, 0, 0);
        }
      }
    }

    // transform acc -> s~ = C_k - 2*dot; track per-lane per-token min
    float Cv[8];
#pragma unroll
    for (int nt = 0; nt < 8; ++nt)
      Cv[nt] = C32g[lvl * KCB + w * 128 + nt * 16 + lc];
    float tmin[2][4];
#pragma unroll
    for (int mt = 0; mt < 2; ++mt)
#pragma unroll
      for (int reg = 0; reg < 4; ++reg) tmin[mt][reg] = 3.4e38f;
#pragma unroll
    for (int mt = 0; mt < 2; ++mt)
#pragma unroll
      for (int nt = 0; nt < 8; ++nt) {
        f32x4 sc;
#pragma unroll
        for (int reg = 0; reg < 4; ++reg) {
          float v = __fsub_rn(Cv[nt], __fmul_rn(2.0f, acc[mt][nt][reg]));
          sc[reg] = v;
          tmin[mt][reg] = fminf(tmin[mt][reg], v);
        }
        acc[mt][nt] = sc;  // keep s~ for append phase
      }
    // wave-local value-min across the 16 cols (xor within 16-lane group)
#pragma unroll
    for (int m = 1; m <= 8; m <<= 1)
#pragma unroll
      for (int mt = 0; mt < 2; ++mt)
#pragma unroll
        for (int reg = 0; reg < 4; ++reg)
          tmin[mt][reg] = fminf(tmin[mt][reg], __shfl_xor(tmin[mt][reg], m));
    if (lc == 0) {
#pragma unroll
      for (int mt = 0; mt < 2; ++mt)
#pragma unroll
        for (int reg = 0; reg < 4; ++reg)
          smin_s[w][mt * 16 + lg * 4 + reg] = tmin[mt][reg];
    }
    __syncthreads();  // B1

    // P3: global screen-min + reset counters
    if (tid < TM) {
      float g = smin_s[0][tid];
#pragma unroll
      for (int ww = 1; ww < 8; ++ww) g = fminf(g, smin_s[ww][tid]);
      gmin_s[tid] = g;
      cnt[tid] = 0;
    }
    __syncthreads();  // B2

    // P4: append window members
#pragma unroll
    for (int mt = 0; mt < 2; ++mt)
#pragma unroll
      for (int reg = 0; reg < 4; ++reg) {
        int t = mt * 16 + lg * 4 + reg;
        float th = gmin_s[t] + WWIN;
#pragma unroll
        for (int nt = 0; nt < 8; ++nt) {
          if (acc[mt][nt][reg] <= th) {
            int slot = atomicAdd(&cnt[t], 1);
            if (slot < LCAP) list[t][slot] = w * 128 + nt * 16 + lc;
          }
        }
      }
    __syncthreads();  // B3

    // P5: np-exact rescore of candidates (16 threads per token)
    {
      int t = tid >> 4;
      int kc = tid & 15;
      float A = A_s[t];
      int n = cnt[t];
      float bd = 3.4e38f;
      int bk = KCB;
      if (n <= LCAP) {
        for (int ci = kc; ci < n; ci += 16) {
          int k = list[t][ci];
          float d = np_dist(&r_m[t][0], cb + (size_t)k * DIM, A,
                            C32g[lvl * KCB + k]);
          if (d < bd || (d == bd && k < bk)) {
            bd = d;
            bk = k;
          }
        }
      }
#pragma unroll
      for (int m = 1; m <= 8; m <<= 1) {
        float od = __shfl_xor(bd, m);
        int ok = __shfl_xor(bk, m);
        if (od < bd || (od == bd && ok < bk)) {
          bd = od;
          bk = ok;
        }
      }
      // safety: overflow or screen/exact disagreement -> full exact scan
      bool redo = (n > LCAP) ||
                  (fabsf(__fsub_rn(bd, A) - gmin_s[t]) > (WWIN - ALARM));
      if (redo) {
        bd = 3.4e38f;
        bk = KCB;
        for (int k = kc; k < KCB; k += 16) {
          float d = np_dist(&r_m[t][0], cb + (size_t)k * DIM, A,
                            C32g[lvl * KCB + k]);
          if (d < bd || (d == bd && k < bk)) {
            bd = d;
            bk = k;
          }
        }
#pragma unroll
        for (int m = 1; m <= 8; m <<= 1) {
          float od = __shfl_xor(bd, m);
          int ok = __shfl_xor(bk, m);
          if (od < bd || (od == bd && ok < bk)) {
            bd = od;
            bk = ok;
          }
        }
      }
      if (kc == 0) {
        idx_s[t] = bk;
        out[(size_t)NTOK * DIM + (size_t)lvl * NTOK + n0 + t] = (float)bk;
      }
    }
    __syncthreads();  // B4

    // P6: residual update (exact) + rb refresh (same thread, same slice)
    {
      int tok = tid >> 4;
      int db = (tid & 15) * 16;
      const float* crow = cb + (size_t)idx_s[tok] * DIM + db;
#pragma unroll
      for (int j = 0; j < 4; ++j) {
        float4 cv4 = *(const float4*)(crow + j * 4);
        int d = db + j * 4;
        float x0 = __fsub_rn(r_m[tok][d + 0], cv4.x);
        float x1 = __fsub_rn(r_m[tok][d + 1], cv4.y);
        float x2 = __fsub_rn(r_m[tok][d + 2], cv4.z);
        float x3 = __fsub_rn(r_m[tok][d + 3], cv4.w);
        r_m[tok][d + 0] = x0;
        r_m[tok][d + 1] = x1;
        r_m[tok][d + 2] = x2;
        r_m[tok][d + 3] = x3;
        rb[tok * RBP + d + 0] = f32_to_bf16_rne(x0);
        rb[tok * RBP + d + 1] = f32_to_bf16_rne(x1);
        rb[tok * RBP + d + 2] = f32_to_bf16_rne(x2);
        rb[tok * RBP + d + 3] = f32_to_bf16_rne(x3);
      }
    }
    __syncthreads();  // B5
  }

  // ---- straight_through = fl(l + fl(q - l)), q = fl(l - r) ----
  {
    int tok = tid >> 4;
    int db = (tid & 15) * 16;
#pragma unroll
    for (int j = 0; j < 4; ++j) {
      int d = db + j * 4;
      size_t gi = (size_t)(n0 + tok) * DIM + d;
      float4 l4 = *(const float4*)(latent + gi);
      float4 qv;
      float q;
      q = __fsub_rn(l4.x, r_m[tok][d + 0]);
      qv.x = __fadd_rn(l4.x, __fsub_rn(q, l4.x));
      q = __fsub_rn(l4.y, r_m[tok][d + 1]);
      qv.y = __fadd_rn(l4.y, __fsub_rn(q, l4.y));
      q = __fsub_rn(l4.z, r_m[tok][d + 2]);
      qv.z = __fadd_rn(l4.z, __fsub_rn(q, l4.z));
      q = __fsub_rn(l4.w, r_m[tok][d + 3]);
      qv.w = __fadd_rn(l4.w, __fsub_rn(q, l4.w));
      *(float4*)(out + gi) = qv;
    }
  }
}

extern "C" void kernel_launch(void* const* d_in, const int* in_sizes, int n_in,
                              void* d_out, int out_size, void* d_ws,
                              size_t ws_size, hipStream_t stream) {
  const float* latent = (const float*)d_in[0];
  const float* codebooks = (const float*)d_in[1];
  float* out = (float*)d_out;
  float* C32g = (float*)d_ws;                       // 32 KB
  unsigned short* cbf = (unsigned short*)((char*)d_ws + 32768);  // 4 MB

  hipLaunchKernelGGL(c2_kernel, dim3(DEPTH * KCB / 256), dim3(256), 0, stream,
                     codebooks, C32g);
  hipLaunchKernelGGL(pack_kernel, dim3(DEPTH * 64 * 8 * 64 / 256), dim3(256),
                     0, stream, codebooks, cbf);
  hipLaunchKernelGGL(rvq_kernel, dim3(NTOK / TM), dim3(512), 0, stream, latent,
                     codebooks, C32g, cbf, out);
}

// Round 16
// 2802.219 us; speedup vs baseline: 2.6080x; 1.1594x over previous
//
#include <hip/hip_runtime.h>

// Residual VQ — bf16-MFMA screen + np-exact rescore. Round 16: break the
// latency wall with 3 independent blocks/CU. 256-thr/4-wave blocks, TM=16,
// two k-passes (acc[8] = 32 VGPR), launch_bounds(256,3) -> VGPR cap 85 ->
// 3 blocks/CU (12 waves). Independent blocks hide each other's screen-load
// latency (the r15 stall: cbf loads at L2/L3 latency with barrier-locked
// waves). Decision arithmetic byte-identical to r14/r15 PASS; pass-0 appends
// use pass-0 min (superset admission, provably safe).
//
// Screen: s~ = C_k - 2*(r~.c~) via mfma_f32_16x16x32_bf16 (RNE bf16).
// Rescore: np-exact chain (validated r4-r15). Safety: overflow/alarm ->
// full exact scan.

#define NTOK 131072
#define DEPTH 8
#define KCB 1024
#define DIM 256
#define TM 16
#define RP 260
#define RBP 264
#define WWIN 0.2f
#define ALARM 0.05f
#define LCAP 64

typedef __attribute__((ext_vector_type(8))) short short8v;
typedef __attribute__((ext_vector_type(4))) float f32x4;

__device__ __forceinline__ unsigned short f32_to_bf16_rne(float f) {
  unsigned int u = __float_as_uint(f);
  return (unsigned short)((u + 0x7FFFu + ((u >> 16) & 1u)) >> 16);
}

__device__ __forceinline__ float np_sumsq_128(const float* p) {
  float s[16];
#pragma unroll
  for (int l = 0; l < 16; ++l) {
    float r0 = __fadd_rn(__fmul_rn(p[l], p[l]),
                         __fmul_rn(p[l + 64], p[l + 64]));
    float r1 = __fadd_rn(__fmul_rn(p[l + 16], p[l + 16]),
                         __fmul_rn(p[l + 80], p[l + 80]));
    float r2 = __fadd_rn(__fmul_rn(p[l + 32], p[l + 32]),
                         __fmul_rn(p[l + 96], p[l + 96]));
    float r3 = __fadd_rn(__fmul_rn(p[l + 48], p[l + 48]),
                         __fmul_rn(p[l + 112], p[l + 112]));
    s[l] = __fadd_rn(__fadd_rn(r0, r1), __fadd_rn(r2, r3));
  }
  float t[8];
#pragma unroll
  for (int l = 0; l < 8; ++l) t[l] = __fadd_rn(s[l], s[l + 8]);
  float u[4];
#pragma unroll
  for (int l = 0; l < 4; ++l) u[l] = __fadd_rn(t[l], t[l + 4]);
  return __fadd_rn(__fadd_rn(u[0], u[2]), __fadd_rn(u[1], u[3]));
}

__device__ __forceinline__ float np_sumsq_256(const float* p) {
  return __fadd_rn(np_sumsq_128(p), np_sumsq_128(p + 128));
}

__device__ __forceinline__ float np_dist(const float* rrow, const float* crow,
                                         float A, float C) {
  float dot = 0.f;
#pragma unroll 8
  for (int q = 0; q < 64; ++q) {
    float4 rv = *(const float4*)(rrow + q * 4);
    float4 cv = *(const float4*)(crow + q * 4);
    dot = fmaf(rv.x, cv.x, dot);
    dot = fmaf(rv.y, cv.y, dot);
    dot = fmaf(rv.z, cv.z, dot);
    dot = fmaf(rv.w, cv.w, dot);
  }
  return __fadd_rn(__fsub_rn(A, __fmul_rn(2.0f, dot)), C);
}

__global__ __launch_bounds__(256) void c2_kernel(const float* __restrict__ cbs,
                                                 float* __restrict__ C32g) {
  int gid = blockIdx.x * 256 + threadIdx.x;
  C32g[gid] = np_sumsq_256(cbs + (size_t)gid * DIM);
}

// cbf[(((lvl*64+g)*8+s)*64+lane)*8 + j] = bf16(cbs[lvl][g*16+(lane&15)]
//                                              [s*32+(lane>>4)*8+j])
__global__ __launch_bounds__(256) void pack_kernel(
    const float* __restrict__ cbs, unsigned short* __restrict__ cbf) {
  int gid = blockIdx.x * 256 + threadIdx.x;  // 262144
  int lane = gid & 63;
  int s = (gid >> 6) & 7;
  int g = (gid >> 9) & 63;
  int lvl = gid >> 15;
  int kcol = g * 16 + (lane & 15);
  int kd0 = s * 32 + (lane >> 4) * 8;
  const float* src = cbs + ((size_t)lvl * KCB + kcol) * DIM + kd0;
  unsigned short t[8];
#pragma unroll
  for (int j = 0; j < 8; ++j) t[j] = f32_to_bf16_rne(src[j]);
  ushort4 lo = {t[0], t[1], t[2], t[3]};
  ushort4 hi = {t[4], t[5], t[6], t[7]};
  *(ushort4*)(cbf + (size_t)gid * 8) = lo;
  *(ushort4*)(cbf + (size_t)gid * 8 + 4) = hi;
}

__global__ __launch_bounds__(256, 3) void rvq_kernel(
    const float* __restrict__ latent, const float* __restrict__ cbs,
    const float* __restrict__ C32g, const unsigned short* __restrict__ cbf,
    float* __restrict__ out) {
  __shared__ float r_m[TM][RP];                          // exact f32 residual
  __shared__ __align__(16) unsigned short rb[TM * RBP];  // bf16 residual
  __shared__ float A_s[TM];
  __shared__ float smin_s[4][TM];
  __shared__ float gmin_s[TM];
  __shared__ int cnt[TM];
  __shared__ int list[TM][LCAP];
  __shared__ int idx_s[TM];

  const int tid = threadIdx.x;
  const int w = tid >> 6;     // 0..3
  const int lane = tid & 63;
  const int lc = lane & 15;   // A-row (token) on input / k-col on output
  const int lg = lane >> 4;   // k-group on input / token-row-group on output
  const int n0 = blockIdx.x * TM;

  // ---- stage latent -> r_m (exact) + rb (bf16) ----
  {
    int tok = tid >> 4;          // 0..15
    int db = (tid & 15) * 16;
    const float* src = latent + (size_t)(n0 + tok) * DIM + db;
#pragma unroll
    for (int j = 0; j < 4; ++j) {
      float4 v = *(const float4*)(src + j * 4);
      *(float4*)&r_m[tok][db + j * 4] = v;
      rb[tok * RBP + db + j * 4 + 0] = f32_to_bf16_rne(v.x);
      rb[tok * RBP + db + j * 4 + 1] = f32_to_bf16_rne(v.y);
      rb[tok * RBP + db + j * 4 + 2] = f32_to_bf16_rne(v.z);
      rb[tok * RBP + db + j * 4 + 3] = f32_to_bf16_rne(v.w);
    }
  }
  __syncthreads();

  for (int lvl = 0; lvl < DEPTH; ++lvl) {
    const float* cb = cbs + (size_t)lvl * KCB * DIM;

    // exact A (np pairwise) — ordered before P5 by intervening barriers
    if (tid < TM) A_s[tid] = np_sumsq_256(&r_m[tid][0]);

    f32x4 acc[8];

#pragma unroll 1
    for (int p = 0; p < 2; ++p) {
      // ---- screen pass p: wave w covers k-tiles g = p*32 + w*8 + nt ----
#pragma unroll
      for (int nt = 0; nt < 8; ++nt) acc[nt] = (f32x4){0.f, 0.f, 0.f, 0.f};
      {
        const unsigned short* bbase =
            cbf + ((((size_t)lvl * 64 + p * 32 + w * 8) * 8) * 64 + lane) * 8;
#pragma unroll
        for (int s = 0; s < 8; ++s) {
          short8v a0 = *(const short8v*)&rb[lc * RBP + s * 32 + lg * 8];
          const unsigned short* bp = bbase + (size_t)s * 64 * 8;
#pragma unroll
          for (int nt = 0; nt < 8; ++nt) {
            short8v bv = *(const short8v*)(bp + (size_t)nt * 8 * 64 * 8);
            acc[nt] = __builtin_amdgcn_mfma_f32_16x16x32_bf16(a0, bv, acc[nt],
                                                              0, 0, 0);
          }
        }
      }
      // transform to s~ = C - 2*dot; per-token min
      float tmin[4];
#pragma unroll
      for (int reg = 0; reg < 4; ++reg) tmin[reg] = 3.4e38f;
#pragma unroll
      for (int nt = 0; nt < 8; ++nt) {
        float Cv = C32g[lvl * KCB + (p * 32 + w * 8 + nt) * 16 + lc];
        f32x4 sc;
#pragma unroll
        for (int reg = 0; reg < 4; ++reg) {
          float v = __fsub_rn(Cv, __fmul_rn(2.0f, acc[nt][reg]));
          sc[reg] = v;
          tmin[reg] = fminf(tmin[reg], v);
        }
        acc[nt] = sc;
      }
#pragma unroll
      for (int m = 1; m <= 8; m <<= 1)
#pragma unroll
        for (int reg = 0; reg < 4; ++reg)
          tmin[reg] = fminf(tmin[reg], __shfl_xor(tmin[reg], m));
      if (lc == 0) {
#pragma unroll
        for (int reg = 0; reg < 4; ++reg)
          smin_s[w][lg * 4 + reg] = tmin[reg];
      }
      __syncthreads();  // pass smins visible

      // min across waves (+ reset counters on pass 0)
      if (tid < TM) {
        float g = smin_s[0][tid];
#pragma unroll
        for (int ww = 1; ww < 4; ++ww) g = fminf(g, smin_s[ww][tid]);
        if (p == 0) {
          gmin_s[tid] = g;
          cnt[tid] = 0;
        } else {
          gmin_s[tid] = fminf(gmin_s[tid], g);
        }
      }
      __syncthreads();  // gmin + cnt ready

      // append window members (pass0 threshold is a superset — safe)
#pragma unroll
      for (int reg = 0; reg < 4; ++reg) {
        int t = lg * 4 + reg;
        float th = gmin_s[t] + WWIN;
#pragma unroll
        for (int nt = 0; nt < 8; ++nt) {
          if (acc[nt][reg] <= th) {
            int slot = atomicAdd(&cnt[t], 1);
            if (slot < LCAP) list[t][slot] = (p * 32 + w * 8 + nt) * 16 + lc;
          }
        }
      }
      __syncthreads();  // appends done before next pass / rescore
    }

    // ---- np-exact rescore of candidates (16 threads per token) ----
    {
      int t = tid >> 4;
      int kc = tid & 15;
      float A = A_s[t];
      int n = cnt[t];
      float bd = 3.4e38f;
      int bk = KCB;
      if (n <= LCAP) {
        for (int ci = kc; ci < n; ci += 16) {
          int k = list[t][ci];
          float d = np_dist(&r_m[t][0], cb + (size_t)k * DIM, A,
                            C32g[lvl * KCB + k]);
          if (d < bd || (d == bd && k < bk)) {
            bd = d;
            bk = k;
          }
        }
      }
#pragma unroll
      for (int m = 1; m <= 8; m <<= 1) {
        float od = __shfl_xor(bd, m);
        int ok = __shfl_xor(bk, m);
        if (od < bd || (od == bd && ok < bk)) {
          bd = od;
          bk = ok;
        }
      }
      bool redo = (n > LCAP) ||
                  (fabsf(__fsub_rn(bd, A) - gmin_s[t]) > (WWIN - ALARM));
      if (redo) {
        bd = 3.4e38f;
        bk = KCB;
        for (int k = kc; k < KCB; k += 16) {
          float d = np_dist(&r_m[t][0], cb + (size_t)k * DIM, A,
                            C32g[lvl * KCB + k]);
          if (d < bd || (d == bd && k < bk)) {
            bd = d;
            bk = k;
          }
        }
#pragma unroll
        for (int m = 1; m <= 8; m <<= 1) {
          float od = __shfl_xor(bd, m);
          int ok = __shfl_xor(bk, m);
          if (od < bd || (od == bd && ok < bk)) {
            bd = od;
            bk = ok;
          }
        }
      }
      if (kc == 0) {
        idx_s[t] = bk;
        out[(size_t)NTOK * DIM + (size_t)lvl * NTOK + n0 + t] = (float)bk;
      }
    }
    __syncthreads();

    // ---- residual update (exact) + rb refresh ----
    {
      int tok = tid >> 4;
      int db = (tid & 15) * 16;
      const float* crow = cb + (size_t)idx_s[tok] * DIM + db;
#pragma unroll
      for (int j = 0; j < 4; ++j) {
        float4 cv4 = *(const float4*)(crow + j * 4);
        int d = db + j * 4;
        float x0 = __fsub_rn(r_m[tok][d + 0], cv4.x);
        float x1 = __fsub_rn(r_m[tok][d + 1], cv4.y);
        float x2 = __fsub_rn(r_m[tok][d + 2], cv4.z);
        float x3 = __fsub_rn(r_m[tok][d + 3], cv4.w);
        r_m[tok][d + 0] = x0;
        r_m[tok][d + 1] = x1;
        r_m[tok][d + 2] = x2;
        r_m[tok][d + 3] = x3;
        rb[tok * RBP + d + 0] = f32_to_bf16_rne(x0);
        rb[tok * RBP + d + 1] = f32_to_bf16_rne(x1);
        rb[tok * RBP + d + 2] = f32_to_bf16_rne(x2);
        rb[tok * RBP + d + 3] = f32_to_bf16_rne(x3);
      }
    }
    __syncthreads();
  }

  // ---- straight_through = fl(l + fl(q - l)), q = fl(l - r) ----
  {
    int tok = tid >> 4;
    int db = (tid & 15) * 16;
#pragma unroll
    for (int j = 0; j < 4; ++j) {
      int d = db + j * 4;
      size_t gi = (size_t)(n0 + tok) * DIM + d;
      float4 l4 = *(const float4*)(latent + gi);
      float4 qv;
      float q;
      q = __fsub_rn(l4.x, r_m[tok][d + 0]);
      qv.x = __fadd_rn(l4.x, __fsub_rn(q, l4.x));
      q = __fsub_rn(l4.y, r_m[tok][d + 1]);
      qv.y = __fadd_rn(l4.y, __fsub_rn(q, l4.y));
      q = __fsub_rn(l4.z, r_m[tok][d + 2]);
      qv.z = __fadd_rn(l4.z, __fsub_rn(q, l4.z));
      q = __fsub_rn(l4.w, r_m[tok][d + 3]);
      qv.w = __fadd_rn(l4.w, __fsub_rn(q, l4.w));
      *(float4*)(out + gi) = qv;
    }
  }
}

extern "C" void kernel_launch(void* const* d_in, const int* in_sizes, int n_in,
                              void* d_out, int out_size, void* d_ws,
                              size_t ws_size, hipStream_t stream) {
  const float* latent = (const float*)d_in[0];
  const float* codebooks = (const float*)d_in[1];
  float* out = (float*)d_out;
  float* C32g = (float*)d_ws;                                    // 32 KB
  unsigned short* cbf = (unsigned short*)((char*)d_ws + 32768);  // 4 MB

  hipLaunchKernelGGL(c2_kernel, dim3(DEPTH * KCB / 256), dim3(256), 0, stream,
                     codebooks, C32g);
  hipLaunchKernelGGL(pack_kernel, dim3(DEPTH * 64 * 8 * 64 / 256), dim3(256),
                     0, stream, codebooks, cbf);
  hipLaunchKernelGGL(rvq_kernel, dim3(NTOK / TM), dim3(256), 0, stream, latent,
                     codebooks, C32g, cbf, out);
}